// Round 4
// baseline (139.539 us; speedup 1.0000x reference)
//
#include <hip/hip_runtime.h>

// AxonalConnections: out[n,b,:,:] = sum over 4 incoming edges (src -> n) of
//   spikes[src,b] * masks[src] * weights[e]
// Topology is compile-time: src(e) = e>>2, dst(e) = (src + (e&3) + 1) & 7.
//
// Round-3 lesson: f32x2 (8 B/lane) kept us at 4.5 TB/s logical — the 6.3 TB/s
// ceiling is a float4 (16 B/lane) number; 8 B accesses double the vector-mem
// instruction count. This version uses f32x4 loads/stores. To keep the
// accumulator from blowing VGPRs (acc[8][4] in f32x4 = 128 regs), the batch
// dimension is split into two passes of 2 batches (acc[8][2] = 64 regs);
// masks+weights are re-read by the 2nd pass from L2/L3 (lines still hot).
// Nontemporal stores keep the 128 MB output from evicting inputs in L3.
// Ideal HBM traffic: 288 MB read + 128 MB write = 416 MB (~66 us @ 6.3 TB/s).

#define HW (1024 * 1024)   // H*W pixels
#define NN 8               // nodes
#define NB 4               // batch

typedef float f32x4 __attribute__((ext_vector_type(4)));

__global__ __launch_bounds__(256, 4) void axon_kernel(
    const float* __restrict__ spikes,   // [N, B, HW]
    const float* __restrict__ masks,    // [N, HW]
    const float* __restrict__ weights,  // [E, HW]
    float* __restrict__ out)            // [N, B, HW]
{
    const int t = blockIdx.x * blockDim.x + threadIdx.x;  // 0 .. HW/4 - 1
    const int p = t * 4;                                  // float offset in a plane

#pragma unroll
    for (int bp = 0; bp < 2; ++bp) {          // batch pair: b = 2*bp, 2*bp+1
        const int b0 = 2 * bp;

        f32x4 acc[NN][2];
#pragma unroll
        for (int n = 0; n < NN; ++n) {
            acc[n][0] = (f32x4)(0.0f);
            acc[n][1] = (f32x4)(0.0f);
        }

#pragma unroll
        for (int src = 0; src < NN; ++src) {
            const f32x4 m = *reinterpret_cast<const f32x4*>(masks + src * HW + p);

            f32x4 s0 = *reinterpret_cast<const f32x4*>(spikes + (src * NB + b0 + 0) * HW + p);
            f32x4 s1 = *reinterpret_cast<const f32x4*>(spikes + (src * NB + b0 + 1) * HW + p);
            s0 *= m;                           // pre-scale by source mask
            s1 *= m;

#pragma unroll
            for (int k = 0; k < 4; ++k) {
                const int e   = src * 4 + k;
                const int dst = (src + k + 1) & 7;
                const f32x4 w = *reinterpret_cast<const f32x4*>(weights + e * HW + p);
#pragma unroll
                for (int c = 0; c < 4; ++c) {
                    acc[dst][0][c] = fmaf(s0[c], w[c], acc[dst][0][c]);
                    acc[dst][1][c] = fmaf(s1[c], w[c], acc[dst][1][c]);
                }
            }
        }

#pragma unroll
        for (int n = 0; n < NN; ++n) {
            __builtin_nontemporal_store(
                acc[n][0], reinterpret_cast<f32x4*>(out + (n * NB + b0 + 0) * HW + p));
            __builtin_nontemporal_store(
                acc[n][1], reinterpret_cast<f32x4*>(out + (n * NB + b0 + 1) * HW + p));
        }
    }
}

extern "C" void kernel_launch(void* const* d_in, const int* in_sizes, int n_in,
                              void* d_out, int out_size, void* d_ws, size_t ws_size,
                              hipStream_t stream) {
    const float* spikes  = (const float*)d_in[0];  // [8,4,1024,1024]
    const float* masks   = (const float*)d_in[1];  // [8,1024,1024]
    const float* weights = (const float*)d_in[2];  // [32,1024,1024]
    float* out = (float*)d_out;                    // [8,4,1024,1024]

    const int threads = 256;
    const int blocks  = (HW / 4) / threads;        // 1024 blocks, 1 thread / 4 pixels
    axon_kernel<<<blocks, threads, 0, stream>>>(spikes, masks, weights, out);
}

// Round 5
// 104.388 us; speedup vs baseline: 1.3367x; 1.3367x over previous
//
#include <hip/hip_runtime.h>

// AxonalConnections: out[n,b,:,:] = sum over 4 incoming edges (src -> n) of
//   spikes[src,b] * masks[src] * weights[e]
// Topology is compile-time: src(e) = e>>2, dst(e) = (src + (e&3) + 1) & 7.
//
// Round-4 lesson: ANY second pass over weights/masks goes to HBM (L2=4MB/XCD,
// streams exceed L3=256MB) -> FETCH jumped 150->271MB and time regressed.
// Round-3 lesson: single-pass f32x2 was latency-bound (VALUBusy 3%, occ 38%).
//
// This version: single pass, f32x4 (16B/lane), and the BATCH dimension lives
// ACROSS LANES instead of across registers:
//   lane l: batch b = l>>4, pixel-group = (wave_id*16 + (l&15)) (4 pixels each)
// Each thread accumulates acc[8] (one batch, all nodes) = 32 VGPR, so the
// whole kernel fits in 64 VGPR -> 8 waves/SIMD (2x round-3 TLP).
// The 4 batch-subgroups read IDENTICAL weight/mask addresses; duplicates
// merge in the wave-level coalescer, so physical traffic stays single-pass:
// 288 MB read + 128 MB write = 416 MB  (~66 us @ 6.3 TB/s).

#define HW (1024 * 1024)   // H*W pixels
#define NN 8               // nodes
#define NB 4               // batch

typedef float f32x4 __attribute__((ext_vector_type(4)));

__global__ __launch_bounds__(256, 8) void axon_kernel(
    const float* __restrict__ spikes,   // [N, B, HW]
    const float* __restrict__ masks,    // [N, HW]
    const float* __restrict__ weights,  // [E, HW]
    float* __restrict__ out)            // [N, B, HW]
{
    const int tid  = blockIdx.x * blockDim.x + threadIdx.x;  // 0 .. HW-1
    const int lane = tid & 63;
    const int b    = lane >> 4;                      // batch from lane group
    const int pg   = (tid >> 6) * 16 + (lane & 15);  // pixel-group (4 pixels)
    const int p    = pg * 4;                         // float offset in a plane

    f32x4 acc[NN];
#pragma unroll
    for (int n = 0; n < NN; ++n) acc[n] = (f32x4)(0.0f);

#pragma unroll
    for (int src = 0; src < NN; ++src) {
        const f32x4 m = *reinterpret_cast<const f32x4*>(masks + src * HW + p);
        f32x4 s = *reinterpret_cast<const f32x4*>(spikes + (src * NB + b) * HW + p);
        s *= m;  // pre-scale by source mask; feeds all 4 outgoing edges

#pragma unroll
        for (int k = 0; k < 4; ++k) {
            const int e   = src * 4 + k;
            const int dst = (src + k + 1) & 7;
            const f32x4 w = *reinterpret_cast<const f32x4*>(weights + e * HW + p);
#pragma unroll
            for (int c = 0; c < 4; ++c)
                acc[dst][c] = fmaf(s[c], w[c], acc[dst][c]);
        }
    }

#pragma unroll
    for (int n = 0; n < NN; ++n)
        __builtin_nontemporal_store(
            acc[n], reinterpret_cast<f32x4*>(out + (n * NB + b) * HW + p));
}

extern "C" void kernel_launch(void* const* d_in, const int* in_sizes, int n_in,
                              void* d_out, int out_size, void* d_ws, size_t ws_size,
                              hipStream_t stream) {
    const float* spikes  = (const float*)d_in[0];  // [8,4,1024,1024]
    const float* masks   = (const float*)d_in[1];  // [8,1024,1024]
    const float* weights = (const float*)d_in[2];  // [32,1024,1024]
    float* out = (float*)d_out;                    // [8,4,1024,1024]

    const int threads = 256;
    const int blocks  = HW / threads;              // 4096 blocks: 1 thread per
    axon_kernel<<<blocks, threads, 0, stream>>>(   // (batch, 4-pixel group)
        spikes, masks, weights, out);
}